// Round 3
// 104.528 us; speedup vs baseline: 1.0181x; 1.0181x over previous
//
#include <hip/hip_runtime.h>

// AttentionLayer: out = softmax(Q @ V^T) @ V ; B=4, SQ=SKV=4096, D=64, fp32.
//
// R16: S=4 REVERT + bit-exact schedule surgery.
// LESSON (R14/R15 post-mortem): R13 passed with absmax EXACTLY 0.03125 == the
// tolerance. S=8 failed TWICE (R14 with defer-max, R15 without) -> S=8's extra
// fp16 partial-combine roundings alone cross the threshold. There is ZERO
// numeric headroom: only bit-exact transforms are admissible. DO NOT raise S;
// DO NOT use defer-max/stale-m (non-bit-exact) without isolated evidence.
//
// Bit-exact changes in R16 (all operand-identical, order-identical FP):
//  1. PV/softmax software pipeline: VT frags of tile t staged into 32 VGPRs
//     at end of iter t; PV(t-1) executes at top of iter t, overlapping (in
//     the wave's schedule) softmax(t)'s max-tree + 2 shfl (~60cy) + 16 exp2
//     (~128cy TRANS). Rescale(t) still follows PV(t-1) via the o-register
//     dependence -> accumulation order unchanged -> bit-identical.
//     (Reg staging also removes the dbuf race: PV(t-1)'s LDS buffer is the
//     DMA(t+1) destination.)
//  2. Lazy exact rescale: skip exp2+16 o-muls iff __all(mn == m_r); fast
//     path uses al = 1.0f in l_r = l_r*al + rs (fma with 1.0 exact).
//  3. s_setprio(1) around MFMA clusters (T5; scheduling only).
// Kept: v_max3 tree (value-identical), combine statically unrolled
// (order-identical), DMA staging, dbuf LDS, one barrier/iter.
// R12 lesson: no __threadfence per block (L2 writeback storm, 7x).

#define NB   4
#define SQ   4096
#define SKV  4096
#define DH   64
#define L2E  1.44269504088896340736f

typedef _Float16 half8 __attribute__((ext_vector_type(8)));
typedef _Float16 half4 __attribute__((ext_vector_type(4)));
typedef _Float16 half2v __attribute__((ext_vector_type(2)));
typedef float f32x4 __attribute__((ext_vector_type(4)));
typedef unsigned short u16;

#define MFMA16(a, b, c) __builtin_amdgcn_mfma_f32_16x16x16f16((a), (b), (c), 0, 0, 0)
#define MFMA32(a, b, c) __builtin_amdgcn_mfma_f32_16x16x32_f16((a), (b), (c), 0, 0, 0)

__device__ __forceinline__ u16 f2h(float f) {
  _Float16 h = (_Float16)f;
  return __builtin_bit_cast(u16, h);
}
__device__ __forceinline__ half2v pkrtz(float a, float b) {
  return __builtin_bit_cast(half2v, __builtin_amdgcn_cvt_pkrtz(a, b));
}
__device__ __forceinline__ float fmax3(float a, float b, float c) {
  return fmaxf(fmaxf(a, b), c);   // clang fuses to v_max3_f32
}

typedef __attribute__((address_space(1))) void gvoid;
typedef __attribute__((address_space(3))) void lvoid;
__device__ __forceinline__ void dma16(const u16* g, u16* l) {
  __builtin_amdgcn_global_load_lds((gvoid*)g, (lvoid*)l, 16, 0, 0);
}

// ---------------------------------------------------------------- prep ----
// V fp32 -> vh fp16 [b][j][d-chunks swizzled by j&7]
//        -> vt fp16 [b][d][per-64-tile: phys chunk h^(d&7), h=(kc2*4+quad),
//                    elem e: kv = kc2*32+(e>>2)*16+quad*4+(e&3)]
__global__ __launch_bounds__(256) void prep_kernel(
    const float* __restrict__ V, u16* __restrict__ vh, u16* __restrict__ vt) {
  __shared__ u16 ldsT[16 * 72];
  int blk = blockIdx.x;
  int b   = blk >> 8;
  int rem = blk & 255;
  int j0  = (rem >> 2) << 6;   // kv tile base
  int d0  = (rem & 3) << 4;    // d tile base
  int t   = threadIdx.x;
  int j   = t >> 2;            // 0..63
  int dc  = (t & 3) << 2;      // 0,4,8,12

  const float* src = V + ((size_t)(b * SKV) + j0 + j) * DH + d0 + dc;
  float4 v4 = *(const float4*)src;
  u16 h[4] = {f2h(v4.x), f2h(v4.y), f2h(v4.z), f2h(v4.w)};
  unsigned p0 = (unsigned)h[0] | ((unsigned)h[1] << 16);
  unsigned p1 = (unsigned)h[2] | ((unsigned)h[3] << 16);
  int dfull = d0 + dc;
  int physd = ((((dfull >> 3) ^ (j & 7)) << 3)) + (dfull & 7);
  *(uint2*)(vh + ((size_t)(b * SKV) + j0 + j) * DH + physd) = make_uint2(p0, p1);

#pragma unroll
  for (int k = 0; k < 4; ++k) ldsT[(dc + k) * 72 + j] = h[k];
  __syncthreads();

  int dl = t >> 4;             // 0..15
  int jc = (t & 15) << 2;      // 0..60 (4 consecutive kv)
  u16 tr[4];
#pragma unroll
  for (int k = 0; k < 4; ++k) tr[k] = ldsT[dl * 72 + jc + k];
  unsigned q0 = (unsigned)tr[0] | ((unsigned)tr[1] << 16);
  unsigned q1 = (unsigned)tr[2] | ((unsigned)tr[3] << 16);
  int d   = d0 + dl;
  int kc2 = jc >> 5;
  int g   = (jc >> 4) & 1;
  int qd  = (jc >> 2) & 3;
  int hp  = ((kc2 << 2) | qd) ^ (d & 7);
  *(uint2*)(vt + ((size_t)(b * DH) + d) * SKV + j0 + (hp << 3) + (g << 2)) =
      make_uint2(q0, q1);
}

// ---------------------------------------------------------------- attn ----
// grid NB*64*S blocks, 256 threads = 4 waves * 16 q-cols each (64 q/block).
__global__ __launch_bounds__(256, 4) void attn_kernel(
    const float* __restrict__ Q,
    const u16* __restrict__ vh,
    const u16* __restrict__ vt,
    u16* __restrict__ po,    // [NB*64*S][64 q][64 d] fp16 unnormalized O
    float* __restrict__ pm,  // [NB*64*S][64] running max (log2 domain)
    float* __restrict__ pl,  // [NB*64*S][64] running sum
    int S, int kvLen) {
  __shared__ __align__(16) u16 lds[2][2][4096];  // [buf][0=V,1=VT], 32 KB

  int blk  = blockIdx.x;
  int tile = blk / S;          // b*64 + qtile
  int s    = blk - tile * S;
  int b    = tile >> 6;
  int q0   = (tile & 63) << 6;
  int kv0  = s * kvLen;
  int t    = threadIdx.x;
  int wave = t >> 6;
  int lane = t & 63;
  int col  = lane & 15;
  int quad = lane >> 4;
  int qw   = q0 + (wave << 4);
  int c7   = col & 7;

  const u16* gv  = vh + (size_t)(b * SKV) * DH;
  const u16* gvt = vt + (size_t)(b * DH) * SKV;

  int r0 = t >> 3;             // DMA row 0..31 (second instr: +32)
  int c0 = (t & 7) << 3;       // DMA chunk elem offset
  int wb = wave << 9;          // wave-uniform LDS dest base (elems)

  // ---- Q fragment as B-operand (n=col=q, k=quad*8+j), log2e folded
  half8 qf[2];
#pragma unroll
  for (int kc = 0; kc < 2; ++kc) {
    const float* qp = Q + ((size_t)(b * SQ) + qw + col) * DH + kc * 32 + (quad << 3);
    float4 a0 = *(const float4*)qp;
    float4 a1 = *(const float4*)(qp + 4);
    half8 hq;
    hq[0] = (_Float16)(a0.x * L2E); hq[1] = (_Float16)(a0.y * L2E);
    hq[2] = (_Float16)(a0.z * L2E); hq[3] = (_Float16)(a0.w * L2E);
    hq[4] = (_Float16)(a1.x * L2E); hq[5] = (_Float16)(a1.y * L2E);
    hq[6] = (_Float16)(a1.z * L2E); hq[7] = (_Float16)(a1.w * L2E);
    qf[kc] = hq;
  }

  f32x4 o[4];                  // O^T frags: d = nf2*16+quad*4+r, q = col
#pragma unroll
  for (int nf = 0; nf < 4; ++nf) o[nf] = (f32x4){0.f, 0.f, 0.f, 0.f};
  float m_r = -1e30f, l_r = 0.f;

  half4 pf[4];                 // P^T frags of CURRENT tile (consumed next iter)
  half8 vr[8];                 // staged VT frags of CURRENT tile (next iter's PV)

  // prologue: DMA tile 0 into buf 0 (drained by first barrier)
  dma16(gv + ((size_t)(kv0 + r0) << 6) + c0,       &lds[0][0][0] + wb);
  dma16(gv + ((size_t)(kv0 + r0 + 32) << 6) + c0,  &lds[0][0][0] + 2048 + wb);
  dma16(gvt + (size_t)r0 * SKV + kv0 + c0,         &lds[0][1][0] + wb);
  dma16(gvt + (size_t)(r0 + 32) * SKV + kv0 + c0,  &lds[0][1][0] + 2048 + wb);

  int nIter = kvLen >> 6;
  int cur = 0;
  for (int it = 0; it < nIter; ++it) {
    __syncthreads();           // drains prior DMA (vmcnt(0)) + buf handoff

    if ((it + 1) < nIter) {    // DMA next tile; hidden under this compute
      int j0n = kv0 + ((it + 1) << 6);
      u16* dv  = &lds[cur ^ 1][0][0];
      u16* dvt = &lds[cur ^ 1][1][0];
      dma16(gv + ((size_t)(j0n + r0) << 6) + c0,      dv + wb);
      dma16(gv + ((size_t)(j0n + r0 + 32) << 6) + c0, dv + 2048 + wb);
      dma16(gvt + (size_t)r0 * SKV + j0n + c0,        dvt + wb);
      dma16(gvt + (size_t)(r0 + 32) * SKV + j0n + c0, dvt + 2048 + wb);
    }

    const u16* sv = &lds[cur][0][0];
    const u16* st = &lds[cur][1][0];

    // ---- S^T = V @ Q^T : sf[nf] covers kv = nf*16 + quad*4 + r
    f32x4 sf[4];
#pragma unroll
    for (int nf = 0; nf < 4; ++nf) sf[nf] = (f32x4){0.f, 0.f, 0.f, 0.f};
    __builtin_amdgcn_s_setprio(1);
#pragma unroll
    for (int nf = 0; nf < 4; ++nf) {
#pragma unroll
      for (int kc = 0; kc < 2; ++kc) {
        int ch = ((kc << 2) | quad) ^ c7;
        half8 av = *(const half8*)(sv + ((nf * 16 + col) << 6) + (ch << 3));
        sf[nf] = MFMA32(av, qf[kc], sf[nf]);
      }
    }
    __builtin_amdgcn_s_setprio(0);

    // ---- PV(t-1) from staged regs: overlaps softmax(t) below in schedule.
    //      Bit-exact reorder: rescale(t) follows via o-register dependence,
    //      so accumulation order is identical to the unpipelined loop.
    if (it > 0) {
      __builtin_amdgcn_s_setprio(1);
#pragma unroll
      for (int kc2 = 0; kc2 < 2; ++kc2) {
#pragma unroll
        for (int nf2 = 0; nf2 < 4; ++nf2) {
          half8 w8 = vr[kc2 * 4 + nf2];
          half4 wlo = __builtin_shufflevector(w8, w8, 0, 1, 2, 3);
          half4 whi = __builtin_shufflevector(w8, w8, 4, 5, 6, 7);
          o[nf2] = MFMA16(wlo, pf[kc2 * 2], o[nf2]);
          o[nf2] = MFMA16(whi, pf[kc2 * 2 + 1], o[nf2]);
        }
      }
      __builtin_amdgcn_s_setprio(0);
    }

    // ---- online softmax(t): exact R13 values; lazy (bit-exact) rescale.
    {
      float t0 = fmax3(sf[0][0], sf[0][1], sf[0][2]);
      float t1 = fmax3(sf[0][3], sf[1][0], sf[1][1]);
      float t2 = fmax3(sf[1][2], sf[1][3], sf[2][0]);
      float t3 = fmax3(sf[2][1], sf[2][2], sf[2][3]);
      float t4 = fmax3(sf[3][0], sf[3][1], sf[3][2]);
      float t5 = fmax3(t0, t1, sf[3][3]);
      float tm = fmax3(t2, t3, t4);
      tm = fmaxf(tm, t5);
      tm = fmaxf(tm, __shfl_xor(tm, 16, 64));
      tm = fmaxf(tm, __shfl_xor(tm, 32, 64));
      float mn = fmaxf(m_r, tm);
      float al = 1.0f;
      if (!__all(mn == m_r)) {   // skip taken => al==1.0 exactly: o*1, l*1
        al = exp2f(m_r - mn);    //   are exact no-ops -> bit-identical skip
        m_r = mn;
#pragma unroll
        for (int nf = 0; nf < 4; ++nf)
#pragma unroll
          for (int r = 0; r < 4; ++r) o[nf][r] *= al;
      }
      float rs = 0.f;
#pragma unroll
      for (int nf = 0; nf < 4; ++nf) {
        float p0 = exp2f(sf[nf][0] - mn);
        float p1 = exp2f(sf[nf][1] - mn);
        float p2 = exp2f(sf[nf][2] - mn);
        float p3 = exp2f(sf[nf][3] - mn);
        rs += (p0 + p1) + (p2 + p3);
        half2v lo = pkrtz(p0, p1);
        half2v hi = pkrtz(p2, p3);
        pf[nf] = __builtin_shufflevector(lo, hi, 0, 1, 2, 3);
      }
      l_r = l_r * al + rs;
    }

    // ---- stage VT(t) into regs for next iter's PV (reads complete before
    //      the next barrier's lgkmcnt(0); buffer is DMA'd only at t+1's top)
#pragma unroll
    for (int kc2 = 0; kc2 < 2; ++kc2) {
#pragma unroll
      for (int nf2 = 0; nf2 < 4; ++nf2) {
        int ch = ((kc2 << 2) | quad) ^ c7;
        vr[kc2 * 4 + nf2] = *(const half8*)(st + ((nf2 * 16 + col) << 6) + (ch << 3));
      }
    }

    cur ^= 1;
  }

  // ---- drain: PV for the last tile
  __builtin_amdgcn_s_setprio(1);
#pragma unroll
  for (int kc2 = 0; kc2 < 2; ++kc2) {
#pragma unroll
    for (int nf2 = 0; nf2 < 4; ++nf2) {
      half8 w8 = vr[kc2 * 4 + nf2];
      half4 wlo = __builtin_shufflevector(w8, w8, 0, 1, 2, 3);
      half4 whi = __builtin_shufflevector(w8, w8, 4, 5, 6, 7);
      o[nf2] = MFMA16(wlo, pf[kc2 * 2], o[nf2]);
      o[nf2] = MFMA16(whi, pf[kc2 * 2 + 1], o[nf2]);
    }
  }
  __builtin_amdgcn_s_setprio(0);

  // ---- epilogue: l reduce across quads, pm/pl, transpose O^T -> po[q][d]
  l_r += __shfl_xor(l_r, 16, 64);
  l_r += __shfl_xor(l_r, 32, 64);
  int pidx = tile * S + s;
  if (quad == 0) {
    pm[(size_t)pidx * 64 + (wave << 4) + col] = m_r;
    pl[(size_t)pidx * 64 + (wave << 4) + col] = l_r;
  }

  __syncthreads();             // tile buffers free; reuse as [64 q][72]
  u16* tp = &lds[0][0][0];
  {
    int qrow = (wave << 4) + col;
#pragma unroll
    for (int nf2 = 0; nf2 < 4; ++nf2) {
#pragma unroll
      for (int r2 = 0; r2 < 4; r2 += 2) {
        unsigned pk = (unsigned)f2h(o[nf2][r2]) |
                      ((unsigned)f2h(o[nf2][r2 + 1]) << 16);
        int d = nf2 * 16 + (quad << 2) + r2;
        *(unsigned*)(tp + qrow * 72 + d) = pk;
      }
    }
  }
  __syncthreads();
  {
    u16* pob = po + (size_t)pidx * 64 * 64;
    int q = t >> 2, hc = (t & 3) << 4;
    uint4 x0 = *(const uint4*)(tp + q * 72 + hc);
    uint4 x1 = *(const uint4*)(tp + q * 72 + hc + 8);
    *(uint4*)(pob + q * 64 + hc)     = x0;
    *(uint4*)(pob + q * 64 + hc + 8) = x1;
  }
}

// ------------------------------------------------------------- combine ----
// grid NB*SQ/32 blocks, 256 threads; thread = (q row, 8-d chunk).
// Statically unrolled (S <= 8, predicated) so mv/lv/w stay in registers;
// iteration order identical to the dynamic loop -> bit-identical at S=4.
__global__ __launch_bounds__(256) void combine_kernel(
    const u16* __restrict__ po,
    const float* __restrict__ pm,
    const float* __restrict__ pl,
    float* __restrict__ out, int S) {
  int t    = threadIdx.x;
  int rowg = blockIdx.x * 32 + (t >> 3);   // global q row
  int tile = rowg >> 6;
  int row  = rowg & 63;
  int dc   = (t & 7) << 3;

  float mv[8], lv[8];
  float M = -1e30f;
#pragma unroll
  for (int s = 0; s < 8; ++s) {
    if (s < S) {
      mv[s] = pm[(size_t)(tile * S + s) * 64 + row];
      lv[s] = pl[(size_t)(tile * S + s) * 64 + row];
      M = fmaxf(M, mv[s]);
    }
  }
  float L = 0.f, w[8];
#pragma unroll
  for (int s = 0; s < 8; ++s) {
    if (s < S) {
      w[s] = exp2f(mv[s] - M);
      L += lv[s] * w[s];
    }
  }
  float acc[8] = {0.f, 0.f, 0.f, 0.f, 0.f, 0.f, 0.f, 0.f};
#pragma unroll
  for (int s = 0; s < 8; ++s) {
    if (s < S) {
      const u16* p = po + (size_t)(tile * S + s) * 4096 + row * 64 + dc;
      uint4 raw = *(const uint4*)p;
      half8 x = __builtin_bit_cast(half8, raw);
#pragma unroll
      for (int k = 0; k < 8; ++k) acc[k] += w[s] * (float)x[k];
    }
  }
  float invL = 1.0f / L;
  float* op = out + (size_t)rowg * 64 + dc;
  f32x4 o0 = (f32x4){acc[0], acc[1], acc[2], acc[3]};
  f32x4 o1 = (f32x4){acc[4], acc[5], acc[6], acc[7]};
  *(f32x4*)op       = o0 * invL;
  *(f32x4*)(op + 4) = o1 * invL;
}

// -------------------------------------------------------------- launch ----
extern "C" void kernel_launch(void* const* d_in, const int* in_sizes, int n_in,
                              void* d_out, int out_size, void* d_ws, size_t ws_size,
                              hipStream_t stream) {
  const float* Q = (const float*)d_in[0];
  const float* V = (const float*)d_in[1];
  float* out = (float*)d_out;

  const size_t convBytes = (size_t)2 * NB * SKV * DH * 2;  // vh+vt = 4 MB
  auto partBytes = [](int S) {
    return (size_t)NB * 64 * S * ((size_t)64 * 64 * 2 + 64 * 8);
  };
  // S pinned to 4: S=8 exceeded the absmax tolerance twice (R14/R15) —
  // the error budget is exactly exhausted at S=4. Do not raise.
  int S = 4;
  while (S > 1 && ws_size < convBytes + partBytes(S)) S >>= 1;
  int kvLen = SKV / S;

  u16* vh = (u16*)d_ws;
  u16* vt = vh + (size_t)NB * SKV * DH;
  u16* po = vt + (size_t)NB * SKV * DH;
  float* pm = (float*)(po + (size_t)NB * 64 * S * 64 * 64);
  float* pl = pm + (size_t)NB * 64 * S * 64;

  prep_kernel<<<NB * 256, 256, 0, stream>>>(V, vh, vt);
  attn_kernel<<<NB * 64 * S, 256, 0, stream>>>(Q, vh, vt, po, pm, pl, S, kvLen);
  combine_kernel<<<NB * SQ / 32, 256, 0, stream>>>(po, pm, pl, out, S);
}